// Round 11
// baseline (839.184 us; speedup 1.0000x reference)
//
#include <hip/hip_runtime.h>
#include <cstddef>

#define G_    128
#define NPG_  256
#define EPG_  4096
#define NN_   32768
#define EE_   524288
#define KK_   2048
#define GK_   262144

// d_out layout (floats): [score E][causal_w GK][conf_w GK][causal_ei 2*GK][conf_ei 2*GK][cmask N][dmask N]
#define O_CW  524288
#define O_DW  786432
#define O_CEI 1048576
#define O_FEI 1572864
#define O_CM  2097152
#define O_DM  2129920

typedef float v4f __attribute__((ext_vector_type(4)));
typedef unsigned long long u64;

struct GemmCfg {
  const float* w[8];
  const float* b[8];
  int wstride;
};

__device__ __forceinline__ void cswap(u64& a, u64& b, bool d) {
  u64 hi = a > b ? a : b, lo = a > b ? b : a;
  a = d ? hi : lo;
  b = d ? lo : hi;
}

// ---------------- GEMM (proven round-6/8 shape — DO NOT vary: nt stores are only safe as
// 256-thr blocks, <=2 blocks/CU resident streams, one column-panel burst per barrier-separated
// cb iteration. Variants (2D grid r7, 512-thr dual-panel r9) hit ~20x HBM write amplification.) ----------------
__global__ __launch_bounds__(256, 4) void gemm_k64(const float* __restrict__ in, int istride,
                                                   GemmCfg cfg, int ncb,
                                                   float* __restrict__ out, int ostride) {
  __shared__ float xT[64 * 68];
  __shared__ float wT[64 * 68];
  const int tid = threadIdx.x;
  const int r0 = blockIdx.x * 64;
  const int wstride = cfg.wstride;
#pragma unroll
  for (int it = 0; it < 16; ++it) {
    int idx = tid + it * 256;
    int rr = idx >> 6, kk = idx & 63;
    xT[kk * 68 + rr] = in[(r0 + rr) * istride + kk];
  }
  const int c4 = (tid & 15) * 4;
  const int r4 = (tid >> 4) * 4;
  for (int cb = 0; cb < ncb; ++cb) {
    const float* wp = cfg.w[cb];
    const float* bp = cfg.b[cb];
    __syncthreads();
#pragma unroll
    for (int it = 0; it < 16; ++it) {
      int idx = tid + it * 256;
      int rr = idx >> 6, kk = idx & 63;
      wT[kk * 68 + rr] = wp[rr * wstride + kk];
    }
    __syncthreads();
    float acc[4][4] = {};
#pragma unroll
    for (int k = 0; k < 64; ++k) {
      float4 xv = *(const float4*)&xT[k * 68 + r4];
      float4 wv = *(const float4*)&wT[k * 68 + c4];
      float xr[4] = {xv.x, xv.y, xv.z, xv.w};
      float wc[4] = {wv.x, wv.y, wv.z, wv.w};
#pragma unroll
      for (int a = 0; a < 4; ++a)
#pragma unroll
        for (int b = 0; b < 4; ++b)
          acc[a][b] = fmaf(xr[a], wc[b], acc[a][b]);
    }
    float bx[4] = {0.f, 0.f, 0.f, 0.f};
    if (bp) {
      float4 bb = *(const float4*)&bp[c4];
      bx[0] = bb.x; bx[1] = bb.y; bx[2] = bb.z; bx[3] = bb.w;
    }
#pragma unroll
    for (int ri = 0; ri < 4; ++ri) {
      v4f st;
      st.x = acc[ri][0] + bx[0];
      st.y = acc[ri][1] + bx[1];
      st.z = acc[ri][2] + bx[2];
      st.w = acc[ri][3] + bx[3];
      __builtin_nontemporal_store(st, (v4f*)&out[(r0 + r4 + ri) * ostride + cb * 64 + c4]);
    }
  }
}

// ---------------- build dense per-group weight matrix MT[g][r][c] += w_e, Wc[col] += w_e ----------------
__global__ __launch_bounds__(256) void build_M(const int* __restrict__ ei, const float* __restrict__ ea,
                                               float* __restrict__ MT, float* __restrict__ Wc) {
  const int e = blockIdx.x * 256 + threadIdx.x;
  const int r = ei[e];
  const int c = ei[EE_ + e];
  const int g = e >> 12;
  const int gb = g << 8;
  const float w = ea[e];
  atomicAdd(&MT[((size_t)g << 16) + ((size_t)(r - gb) << 8) + (c - gb)], w);
  atomicAdd(&Wc[c], w);
}

// ---------------- dense leconv aggregation (round-6 proven): h[c] = sum_r MT[r][c]*A[r] - Wc[c]*B[c] + C[c] ----------------
__global__ __launch_bounds__(256) void mm_agg(const float* __restrict__ MT, const float* __restrict__ buf,
                                              const float* __restrict__ Wc, float* __restrict__ hout,
                                              int do_relu) {
  __shared__ float Ms[64 * 72];
  __shared__ float As[64 * 72];
  const int tid = threadIdx.x;
  const int g = blockIdx.x >> 2;
  const int c0 = (blockIdx.x & 3) * 64;
  const int gbase = g * NPG_;
  const size_t mbase = (size_t)g << 16;
  const int c4 = (tid >> 4) * 4;   // output node within tile
  const int k4 = (tid & 15) * 4;   // feature (lane-contiguous)
  float acc[4][4] = {};
  for (int kc = 0; kc < 4; ++kc) {
#pragma unroll
    for (int it = 0; it < 16; ++it) {
      int idx = tid + it * 256;
      int rr = idx >> 6, cc = idx & 63;
      Ms[rr * 72 + cc] = MT[mbase + (size_t)(kc * 64 + rr) * 256 + c0 + cc];
      As[rr * 72 + cc] = buf[(gbase + kc * 64 + rr) * 192 + cc];
    }
    __syncthreads();
#pragma unroll
    for (int r = 0; r < 64; ++r) {
      float4 mv = *(const float4*)&Ms[r * 72 + c4];
      float4 av = *(const float4*)&As[r * 72 + k4];
      float mr[4] = {mv.x, mv.y, mv.z, mv.w};
      float ak[4] = {av.x, av.y, av.z, av.w};
#pragma unroll
      for (int ci = 0; ci < 4; ++ci)
#pragma unroll
        for (int ki = 0; ki < 4; ++ki)
          acc[ci][ki] = fmaf(mr[ci], ak[ki], acc[ci][ki]);
    }
    __syncthreads();
  }
#pragma unroll
  for (int ci = 0; ci < 4; ++ci) {
    int n = gbase + c0 + c4 + ci;
    float wcn = Wc[n];
    float4 b4 = *(const float4*)&buf[n * 192 + 64 + k4];
    float4 cc4 = *(const float4*)&buf[n * 192 + 128 + k4];
    float4 st;
    st.x = acc[ci][0] - wcn * b4.x + cc4.x;
    st.y = acc[ci][1] - wcn * b4.y + cc4.y;
    st.z = acc[ci][2] - wcn * b4.z + cc4.z;
    st.w = acc[ci][3] - wcn * b4.w + cc4.w;
    if (do_relu) {
      st.x = fmaxf(st.x, 0.f); st.y = fmaxf(st.y, 0.f);
      st.z = fmaxf(st.z, 0.f); st.w = fmaxf(st.w, 0.f);
    }
    *(float4*)&hout[n * 64 + k4] = st;
  }
}

// ---------------- fused P/Q + edge scores: no pq materialization ----------------
// Lane owns node tid: h2 row in 64 VGPRs (loaded once). Per 16-out chunk: compute P/Q via
// register FMA with scalar-loaded (block-uniform) Wm1 rows; stage into Ps/Qs; gather 8 edges/lane.
__global__ __launch_bounds__(256) void score_fused(const float* __restrict__ h_c, const int* __restrict__ ei,
                                                   const float* __restrict__ wm1, const float* __restrict__ bm1,
                                                   const float* __restrict__ wm2, const float* __restrict__ bm2,
                                                   float* __restrict__ out) {
  __shared__ float Ps[256 * 20];  // 20 KB
  __shared__ float Qs[256 * 20];  // 20 KB
  const int tid = threadIdx.x;
  const int g = blockIdx.x & 127;        // pair {g, g+128} -> same XCD for h_c L2 reuse
  const int half = blockIdx.x >> 7;
  const int gbase = g * NPG_;
  const int ebase = g * EPG_ + half * 2048;
  float4 hr[16];
  {
    const float* hp = &h_c[(size_t)(gbase + tid) * 64];
#pragma unroll
    for (int i = 0; i < 16; ++i) hr[i] = *(const float4*)&hp[i * 4];
  }
  int rl[8], cl[8];
  float accE[8] = {};
#pragma unroll
  for (int j = 0; j < 8; ++j) {
    int e = ebase + j * 256 + tid;
    rl[j] = (ei[e] - gbase) * 20;
    cl[j] = (ei[EE_ + e] - gbase) * 20;
  }
  for (int t = 0; t < 16; ++t) {
    float accP[16], accQ[16];
#pragma unroll
    for (int j = 0; j < 16; ++j) {
      const float* rowP = &wm1[(size_t)(t * 16 + j) * 128];      // block-uniform -> s_load
      const float* rowQ = rowP + 64;
      float aP = 0.f, aQ = 0.f;
#pragma unroll
      for (int k4 = 0; k4 < 16; ++k4) {
        float4 h4 = hr[k4];
        aP = fmaf(h4.x, rowP[k4 * 4 + 0], aP);
        aP = fmaf(h4.y, rowP[k4 * 4 + 1], aP);
        aP = fmaf(h4.z, rowP[k4 * 4 + 2], aP);
        aP = fmaf(h4.w, rowP[k4 * 4 + 3], aP);
        aQ = fmaf(h4.x, rowQ[k4 * 4 + 0], aQ);
        aQ = fmaf(h4.y, rowQ[k4 * 4 + 1], aQ);
        aQ = fmaf(h4.z, rowQ[k4 * 4 + 2], aQ);
        aQ = fmaf(h4.w, rowQ[k4 * 4 + 3], aQ);
      }
      accP[j] = aP + bm1[t * 16 + j];
      accQ[j] = aQ;
    }
    __syncthreads();  // previous chunk's gather done before overwriting Ps/Qs
#pragma unroll
    for (int j4 = 0; j4 < 16; j4 += 4) {
      float4 sp = {accP[j4], accP[j4 + 1], accP[j4 + 2], accP[j4 + 3]};
      float4 sq = {accQ[j4], accQ[j4 + 1], accQ[j4 + 2], accQ[j4 + 3]};
      *(float4*)&Ps[tid * 20 + j4] = sp;
      *(float4*)&Qs[tid * 20 + j4] = sq;
    }
    __syncthreads();
#pragma unroll
    for (int k4 = 0; k4 < 16; k4 += 4) {
      float4 w4 = *(const float4*)&wm2[t * 16 + k4];             // uniform -> s_load
#pragma unroll
      for (int j = 0; j < 8; ++j) {
        float4 p = *(const float4*)&Ps[rl[j] + k4];
        float4 q = *(const float4*)&Qs[cl[j] + k4];
        accE[j] = fmaf(w4.x, fmaxf(p.x + q.x, 0.f), accE[j]);
        accE[j] = fmaf(w4.y, fmaxf(p.y + q.y, 0.f), accE[j]);
        accE[j] = fmaf(w4.z, fmaxf(p.z + q.z, 0.f), accE[j]);
        accE[j] = fmaf(w4.w, fmaxf(p.w + q.w, 0.f), accE[j]);
      }
    }
  }
  const float beta = bm2[0];
#pragma unroll
  for (int j = 0; j < 8; ++j) out[ebase + j * 256 + tid] = accE[j] + beta;
}

// ---------------- bitonic argsort v3: j<=2 steps fused in-register on thread-owned quads ----------------
__global__ __launch_bounds__(1024) void sort_kernel(float* __restrict__ out, const int* __restrict__ ei,
                                                    int* __restrict__ kg, int* __restrict__ dg,
                                                    int* __restrict__ cmask, int* __restrict__ dmask) {
  __shared__ u64 keys[EPG_];
  const int g = blockIdx.x;
  const int tid = threadIdx.x;
  for (int i = tid; i < EPG_; i += 1024) {
    float s = out[g * EPG_ + i];
    unsigned u = __float_as_uint(s);
    u = (u & 0x80000000u) ? ~u : (u | 0x80000000u);
    keys[i] = ((u64)u << 32) | (unsigned)(~i);
  }
  __syncthreads();
  const int b = 4 * tid;
  {  // k=2 phase (j=1)
    u64 e0 = keys[b], e1 = keys[b + 1], e2 = keys[b + 2], e3 = keys[b + 3];
    cswap(e0, e1, true);
    cswap(e2, e3, false);
    keys[b] = e0; keys[b + 1] = e1; keys[b + 2] = e2; keys[b + 3] = e3;
  }
  __syncthreads();
  {  // k=4 phase (j=2,1)
    bool d = ((b & 4) == 0);
    u64 e0 = keys[b], e1 = keys[b + 1], e2 = keys[b + 2], e3 = keys[b + 3];
    cswap(e0, e2, d); cswap(e1, e3, d);
    cswap(e0, e1, d); cswap(e2, e3, d);
    keys[b] = e0; keys[b + 1] = e1; keys[b + 2] = e2; keys[b + 3] = e3;
  }
  __syncthreads();
  for (int k = 8; k <= EPG_; k <<= 1) {
    for (int j = k >> 1; j >= 4; j >>= 1) {
      const int jm1 = j - 1;
      const int p0 = tid, p1 = tid + 1024;
      const int i0 = ((p0 & ~jm1) << 1) | (p0 & jm1);
      const int i1 = ((p1 & ~jm1) << 1) | (p1 & jm1);
      u64 a0 = keys[i0], b0 = keys[i0 + j];
      u64 a1 = keys[i1], b1 = keys[i1 + j];
      bool d0 = ((i0 & k) == 0), d1 = ((i1 & k) == 0);
      u64 hi0 = a0 > b0 ? a0 : b0, lo0 = a0 > b0 ? b0 : a0;
      u64 hi1 = a1 > b1 ? a1 : b1, lo1 = a1 > b1 ? b1 : a1;
      keys[i0]     = d0 ? hi0 : lo0;
      keys[i0 + j] = d0 ? lo0 : hi0;
      keys[i1]     = d1 ? hi1 : lo1;
      keys[i1 + j] = d1 ? lo1 : hi1;
      __syncthreads();
    }
    {  // j=2,1 fused in-register
      bool d = ((b & k) == 0);
      u64 e0 = keys[b], e1 = keys[b + 1], e2 = keys[b + 2], e3 = keys[b + 3];
      cswap(e0, e2, d); cswap(e1, e3, d);
      cswap(e0, e1, d); cswap(e2, e3, d);
      keys[b] = e0; keys[b + 1] = e1; keys[b + 2] = e2; keys[b + 3] = e3;
    }
    __syncthreads();
  }
  for (int p = tid; p < EPG_; p += 1024) {
    u64 kv = keys[p];
    int i = (int)(~(unsigned)kv);
    unsigned hi = (unsigned)(kv >> 32);
    unsigned ub = (hi & 0x80000000u) ? (hi ^ 0x80000000u) : ~hi;
    float s = __uint_as_float(ub);
    int e = g * EPG_ + i;
    int r = ei[e], c = ei[EE_ + e];
    if (p < KK_) {
      out[O_CW + g * KK_ + p] = s;
      kg[g * KK_ + p] = e;
      cmask[r] = 1; cmask[c] = 1;
    } else {
      int q = p - KK_;
      out[O_DW + g * KK_ + q] = -s;
      dg[g * KK_ + q] = e;
      dmask[r] = 1; dmask[c] = 1;
    }
  }
}

// ---------------- inclusive scan of masks -> nid (cumsum-1); 1 block per mask ----------------
__global__ __launch_bounds__(1024) void scan_kernel(const int* __restrict__ masks, int* __restrict__ nids) {
  const int which = blockIdx.x;
  const int* m = masks + which * NN_;
  int* nid = nids + which * NN_;
  const int tid = threadIdx.x;
  const int base = tid * 32;
  int local[32];
  int sum = 0;
#pragma unroll
  for (int j = 0; j < 32; ++j) { local[j] = m[base + j]; sum += local[j]; }
  __shared__ int ps[1024];
  ps[tid] = sum;
  __syncthreads();
  for (int off = 1; off < 1024; off <<= 1) {
    int v = (tid >= off) ? ps[tid - off] : 0;
    __syncthreads();
    ps[tid] += v;
    __syncthreads();
  }
  int run = ps[tid] - sum;
#pragma unroll
  for (int j = 0; j < 32; ++j) { run += local[j]; nid[base + j] = run - 1; }
}

// ---------------- final gathers ----------------
__global__ __launch_bounds__(256) void finalize_kernel(const int* __restrict__ kg, const int* __restrict__ dg,
                                                       const int* __restrict__ ei,
                                                       const int* __restrict__ nid_c, const int* __restrict__ nid_d,
                                                       const int* __restrict__ cmask, const int* __restrict__ dmask,
                                                       float* __restrict__ out) {
  const int p = blockIdx.x * 256 + threadIdx.x;
  int e = kg[p];
  out[O_CEI + p]       = (float)nid_c[ei[e]];
  out[O_CEI + GK_ + p] = (float)nid_c[ei[EE_ + e]];
  int e2 = dg[p];
  out[O_FEI + p]       = (float)nid_d[ei[e2]];
  out[O_FEI + GK_ + p] = (float)nid_d[ei[EE_ + e2]];
  if (p < NN_) {
    out[O_CM + p] = (float)cmask[p];
    out[O_DM + p] = (float)dmask[p];
  }
}

extern "C" void kernel_launch(void* const* d_in, const int* in_sizes, int n_in,
                              void* d_out, int out_size, void* d_ws, size_t ws_size,
                              hipStream_t stream) {
  (void)in_sizes; (void)n_in; (void)out_size; (void)ws_size;
  const float* x   = (const float*)d_in[0];
  const float* ea  = (const float*)d_in[1];
  const float* W11 = (const float*)d_in[2];
  const float* b11 = (const float*)d_in[3];
  const float* W12 = (const float*)d_in[4];
  const float* W13 = (const float*)d_in[5];
  const float* b13 = (const float*)d_in[6];
  const float* W21 = (const float*)d_in[7];
  const float* b21 = (const float*)d_in[8];
  const float* W22 = (const float*)d_in[9];
  const float* W23 = (const float*)d_in[10];
  const float* b23 = (const float*)d_in[11];
  const float* Wm1 = (const float*)d_in[12];
  const float* bm1 = (const float*)d_in[13];
  const float* Wm2 = (const float*)d_in[14];
  const float* bm2 = (const float*)d_in[15];
  const int*   ei  = (const int*)d_in[16];
  float* out = (float*)d_out;
  float* ws  = (float*)d_ws;

  // workspace (float offsets):
  //   MT  [0, 8388608)          32 MB
  //   Wc  [8388608, 8421376)    128 KB  adjacent to MT -> single fused memset
  //   buf [8421376, 14712832)   24 MB
  //   h_c [16777216, 18874368)  8 MB
  //   ints from 18874368: kg GK, dg GK, cmask N, dmask N, nid_c N, nid_d N
  float* MT  = ws;
  float* Wc  = ws + 8388608;
  float* buf = ws + 8421376;
  float* h_c = ws + 16777216;
  int* kg    = (int*)(ws + 18874368);
  int* dg    = kg + GK_;
  int* cmask = dg + GK_;
  int* dmask = cmask + NN_;
  int* nid_c = dmask + NN_;
  int* nid_d = nid_c + NN_;

  (void)hipMemsetAsync(MT, 0, (size_t)(8388608 + 32768) * sizeof(float), stream);  // MT + Wc
  (void)hipMemsetAsync(cmask, 0, 2 * NN_ * sizeof(int), stream);

  build_M<<<EE_ / 256, 256, 0, stream>>>(ei, ea, MT, Wc);

  GemmCfg c1{};
  c1.w[0] = W11; c1.w[1] = W12; c1.w[2] = W13;
  c1.b[0] = b11; c1.b[1] = nullptr; c1.b[2] = b13;
  c1.wstride = 64;
  gemm_k64<<<512, 256, 0, stream>>>(x, 64, c1, 3, buf, 192);

  mm_agg<<<512, 256, 0, stream>>>(MT, buf, Wc, h_c, /*relu=*/1);

  GemmCfg c2{};
  c2.w[0] = W21; c2.w[1] = W22; c2.w[2] = W23;
  c2.b[0] = b21; c2.b[1] = nullptr; c2.b[2] = b23;
  c2.wstride = 64;
  gemm_k64<<<512, 256, 0, stream>>>(h_c, 64, c2, 3, buf, 192);

  mm_agg<<<512, 256, 0, stream>>>(MT, buf, Wc, h_c, /*relu=*/0);

  score_fused<<<256, 256, 0, stream>>>(h_c, ei, Wm1, bm1, Wm2, bm2, out);

  sort_kernel<<<G_, 1024, 0, stream>>>(out, ei, kg, dg, cmask, dmask);

  scan_kernel<<<2, 1024, 0, stream>>>(cmask, nid_c);

  finalize_kernel<<<GK_ / 256, 256, 0, stream>>>(kg, dg, ei, nid_c, nid_d, cmask, dmask, out);
}

// Round 12
// 400.785 us; speedup vs baseline: 2.0939x; 2.0939x over previous
//
#include <hip/hip_runtime.h>
#include <cstddef>

#define G_    128
#define NPG_  256
#define EPG_  4096
#define NN_   32768
#define EE_   524288
#define KK_   2048
#define GK_   262144

// d_out layout (floats): [score E][causal_w GK][conf_w GK][causal_ei 2*GK][conf_ei 2*GK][cmask N][dmask N]
#define O_CW  524288
#define O_DW  786432
#define O_CEI 1048576
#define O_FEI 1572864
#define O_CM  2097152
#define O_DM  2129920

typedef float v4f __attribute__((ext_vector_type(4)));
typedef unsigned long long u64;

struct GemmCfg {
  const float* w[8];
  const float* b[8];
  int wstride;
};

__device__ __forceinline__ void cswap(u64& a, u64& b, bool d) {
  u64 hi = a > b ? a : b, lo = a > b ? b : a;
  a = d ? hi : lo;
  b = d ? lo : hi;
}

// ---------------- GEMM (proven round-6/8 shape — DO NOT vary: nt stores are only safe as
// 256-thr blocks, <=2 blocks/CU resident streams, one column-panel burst per barrier-separated
// cb iteration. Variants (2D grid r7, 512-thr dual-panel r9) hit ~20x HBM write amplification.) ----------------
__global__ __launch_bounds__(256, 4) void gemm_k64(const float* __restrict__ in, int istride,
                                                   GemmCfg cfg, int ncb,
                                                   float* __restrict__ out, int ostride) {
  __shared__ float xT[64 * 68];
  __shared__ float wT[64 * 68];
  const int tid = threadIdx.x;
  const int r0 = blockIdx.x * 64;
  const int wstride = cfg.wstride;
#pragma unroll
  for (int it = 0; it < 16; ++it) {
    int idx = tid + it * 256;
    int rr = idx >> 6, kk = idx & 63;
    xT[kk * 68 + rr] = in[(r0 + rr) * istride + kk];
  }
  const int c4 = (tid & 15) * 4;
  const int r4 = (tid >> 4) * 4;
  for (int cb = 0; cb < ncb; ++cb) {
    const float* wp = cfg.w[cb];
    const float* bp = cfg.b[cb];
    __syncthreads();
#pragma unroll
    for (int it = 0; it < 16; ++it) {
      int idx = tid + it * 256;
      int rr = idx >> 6, kk = idx & 63;
      wT[kk * 68 + rr] = wp[rr * wstride + kk];
    }
    __syncthreads();
    float acc[4][4] = {};
#pragma unroll
    for (int k = 0; k < 64; ++k) {
      float4 xv = *(const float4*)&xT[k * 68 + r4];
      float4 wv = *(const float4*)&wT[k * 68 + c4];
      float xr[4] = {xv.x, xv.y, xv.z, xv.w};
      float wc[4] = {wv.x, wv.y, wv.z, wv.w};
#pragma unroll
      for (int a = 0; a < 4; ++a)
#pragma unroll
        for (int b = 0; b < 4; ++b)
          acc[a][b] = fmaf(xr[a], wc[b], acc[a][b]);
    }
    float bx[4] = {0.f, 0.f, 0.f, 0.f};
    if (bp) {
      float4 bb = *(const float4*)&bp[c4];
      bx[0] = bb.x; bx[1] = bb.y; bx[2] = bb.z; bx[3] = bb.w;
    }
#pragma unroll
    for (int ri = 0; ri < 4; ++ri) {
      v4f st;
      st.x = acc[ri][0] + bx[0];
      st.y = acc[ri][1] + bx[1];
      st.z = acc[ri][2] + bx[2];
      st.w = acc[ri][3] + bx[3];
      __builtin_nontemporal_store(st, (v4f*)&out[(r0 + r4 + ri) * ostride + cb * 64 + c4]);
    }
  }
}

// ---------------- build dense per-group weight matrix MT[g][r][c] += w_e, Wc[col] += w_e ----------------
__global__ __launch_bounds__(256) void build_M(const int* __restrict__ ei, const float* __restrict__ ea,
                                               float* __restrict__ MT, float* __restrict__ Wc) {
  const int e = blockIdx.x * 256 + threadIdx.x;
  const int r = ei[e];
  const int c = ei[EE_ + e];
  const int g = e >> 12;
  const int gb = g << 8;
  const float w = ea[e];
  atomicAdd(&MT[((size_t)g << 16) + ((size_t)(r - gb) << 8) + (c - gb)], w);
  atomicAdd(&Wc[c], w);
}

// ---------------- dense leconv aggregation (round-6 proven): h[c] = sum_r MT[r][c]*A[r] - Wc[c]*B[c] + C[c] ----------------
__global__ __launch_bounds__(256) void mm_agg(const float* __restrict__ MT, const float* __restrict__ buf,
                                              const float* __restrict__ Wc, float* __restrict__ hout,
                                              int do_relu) {
  __shared__ float Ms[64 * 72];
  __shared__ float As[64 * 72];
  const int tid = threadIdx.x;
  const int g = blockIdx.x >> 2;
  const int c0 = (blockIdx.x & 3) * 64;
  const int gbase = g * NPG_;
  const size_t mbase = (size_t)g << 16;
  const int c4 = (tid >> 4) * 4;   // output node within tile
  const int k4 = (tid & 15) * 4;   // feature (lane-contiguous)
  float acc[4][4] = {};
  for (int kc = 0; kc < 4; ++kc) {
#pragma unroll
    for (int it = 0; it < 16; ++it) {
      int idx = tid + it * 256;
      int rr = idx >> 6, cc = idx & 63;
      Ms[rr * 72 + cc] = MT[mbase + (size_t)(kc * 64 + rr) * 256 + c0 + cc];
      As[rr * 72 + cc] = buf[(gbase + kc * 64 + rr) * 192 + cc];
    }
    __syncthreads();
#pragma unroll
    for (int r = 0; r < 64; ++r) {
      float4 mv = *(const float4*)&Ms[r * 72 + c4];
      float4 av = *(const float4*)&As[r * 72 + k4];
      float mr[4] = {mv.x, mv.y, mv.z, mv.w};
      float ak[4] = {av.x, av.y, av.z, av.w};
#pragma unroll
      for (int ci = 0; ci < 4; ++ci)
#pragma unroll
        for (int ki = 0; ki < 4; ++ki)
          acc[ci][ki] = fmaf(mr[ci], ak[ki], acc[ci][ki]);
    }
    __syncthreads();
  }
#pragma unroll
  for (int ci = 0; ci < 4; ++ci) {
    int n = gbase + c0 + c4 + ci;
    float wcn = Wc[n];
    float4 b4 = *(const float4*)&buf[n * 192 + 64 + k4];
    float4 cc4 = *(const float4*)&buf[n * 192 + 128 + k4];
    float4 st;
    st.x = acc[ci][0] - wcn * b4.x + cc4.x;
    st.y = acc[ci][1] - wcn * b4.y + cc4.y;
    st.z = acc[ci][2] - wcn * b4.z + cc4.z;
    st.w = acc[ci][3] - wcn * b4.w + cc4.w;
    if (do_relu) {
      st.x = fmaxf(st.x, 0.f); st.y = fmaxf(st.y, 0.f);
      st.z = fmaxf(st.z, 0.f); st.w = fmaxf(st.w, 0.f);
    }
    *(float4*)&hout[n * 64 + k4] = st;
  }
}

// ---------------- fused edge scores v4 (round-10 proven): node-major padded LDS, b128 gathers ----------------
__global__ __launch_bounds__(256, 4) void score_v4(const float* __restrict__ pq, const int* __restrict__ ei,
                                                   const float* __restrict__ wm2, const float* __restrict__ bm2,
                                                   float* __restrict__ out) {
  __shared__ float Ps[256 * 20];  // 20 KB
  __shared__ float Qs[256 * 20];  // 20 KB
  const int tid = threadIdx.x;
  const int g = blockIdx.x & 127;
  const int quarter = blockIdx.x >> 7;
  const int gbase = g * NPG_;
  const int ebase = g * EPG_ + quarter * 1024;
  int rl[4], cl[4];
  float acc[4] = {};
#pragma unroll
  for (int j = 0; j < 4; ++j) {
    int e = ebase + j * 256 + tid;
    rl[j] = (ei[e] - gbase) * 20;
    cl[j] = (ei[EE_ + e] - gbase) * 20;
  }
  for (int t = 0; t < 16; ++t) {
    __syncthreads();
#pragma unroll
    for (int it = 0; it < 4; ++it) {
      int idx = tid + it * 256;
      int node = idx >> 2, k4 = (idx & 3) * 4;
      const float* src = &pq[(size_t)(gbase + node) * 512 + t * 16 + k4];
      *(float4*)&Ps[node * 20 + k4] = *(const float4*)src;
      *(float4*)&Qs[node * 20 + k4] = *(const float4*)(src + 256);
    }
    __syncthreads();
#pragma unroll
    for (int k4 = 0; k4 < 16; k4 += 4) {
      float4 w4 = *(const float4*)&wm2[t * 16 + k4];
#pragma unroll
      for (int j = 0; j < 4; ++j) {
        float4 p = *(const float4*)&Ps[rl[j] + k4];
        float4 q = *(const float4*)&Qs[cl[j] + k4];
        acc[j] = fmaf(w4.x, fmaxf(p.x + q.x, 0.f), acc[j]);
        acc[j] = fmaf(w4.y, fmaxf(p.y + q.y, 0.f), acc[j]);
        acc[j] = fmaf(w4.z, fmaxf(p.z + q.z, 0.f), acc[j]);
        acc[j] = fmaf(w4.w, fmaxf(p.w + q.w, 0.f), acc[j]);
      }
    }
  }
  const float beta = bm2[0];
#pragma unroll
  for (int j = 0; j < 4; ++j) out[ebase + j * 256 + tid] = acc[j] + beta;
}

// ---------------- bitonic argsort v4: thread owns 4 els in registers; k<=256 phases via shfl_xor
// (wave-synchronous, zero barriers); only j>=256 steps through LDS (10 steps, ~14 barriers) ----------------
__global__ __launch_bounds__(1024) void sort_kernel(float* __restrict__ out, const int* __restrict__ ei,
                                                    int* __restrict__ kg, int* __restrict__ dg,
                                                    int* __restrict__ cmask, int* __restrict__ dmask) {
  __shared__ u64 keys[EPG_];
  const int g = blockIdx.x;
  const int tid = threadIdx.x;
  const int b = 4 * tid;
  u64 e[4];
  {
    float4 s4 = *(const float4*)&out[g * EPG_ + b];
    float sv[4] = {s4.x, s4.y, s4.z, s4.w};
#pragma unroll
    for (int s = 0; s < 4; ++s) {
      unsigned u = __float_as_uint(sv[s]);
      u = (u & 0x80000000u) ? ~u : (u | 0x80000000u);
      e[s] = ((u64)u << 32) | (unsigned)(~(b + s));
    }
  }
  // k=2 phase (j=1): (b,b+1) desc, (b+2,b+3) asc
  cswap(e[0], e[1], true);
  cswap(e[2], e[3], false);
  // k=4 phase (j=2,1): dir constant over quad
  {
    bool d = ((b & 4) == 0);
    cswap(e[0], e[2], d); cswap(e[1], e[3], d);
    cswap(e[0], e[1], d); cswap(e[2], e[3], d);
  }
  // phases k=8..4096
  for (int k = 8; k <= EPG_; k <<= 1) {
    // cross-wave steps (j >= 256) through LDS
    if (k >= 512) {
#pragma unroll
      for (int s = 0; s < 4; ++s) keys[b + s] = e[s];
      __syncthreads();
      for (int j = k >> 1; j >= 256; j >>= 1) {
        const int jm1 = j - 1;
        const int p0 = tid, p1 = tid + 1024;
        const int i0 = ((p0 & ~jm1) << 1) | (p0 & jm1);
        const int i1 = ((p1 & ~jm1) << 1) | (p1 & jm1);
        u64 a0 = keys[i0], b0 = keys[i0 + j];
        u64 a1 = keys[i1], b1 = keys[i1 + j];
        bool d0 = ((i0 & k) == 0), d1 = ((i1 & k) == 0);
        u64 hi0 = a0 > b0 ? a0 : b0, lo0 = a0 > b0 ? b0 : a0;
        u64 hi1 = a1 > b1 ? a1 : b1, lo1 = a1 > b1 ? b1 : a1;
        keys[i0]     = d0 ? hi0 : lo0;
        keys[i0 + j] = d0 ? lo0 : hi0;
        keys[i1]     = d1 ? hi1 : lo1;
        keys[i1 + j] = d1 ? lo1 : hi1;
        __syncthreads();
      }
#pragma unroll
      for (int s = 0; s < 4; ++s) e[s] = keys[b + s];
      // after the final barrier above, all remaining accesses are thread-private slots
    }
    const bool d = ((tid & (k >> 2)) == 0);  // = ((i & k) == 0) for this thread's quad (k >= 8)
    // within-wave steps j = min(k/2,128) .. 4 via shfl_xor
    for (int j = (k >> 1) > 128 ? 128 : (k >> 1); j >= 4; j >>= 1) {
      const int delta = j >> 2;
      const bool lower = ((tid & delta) == 0);
      const bool keepmax = (lower == d);
#pragma unroll
      for (int s = 0; s < 4; ++s) {
        u64 p = __shfl_xor(e[s], delta);
        u64 mx = e[s] > p ? e[s] : p;
        u64 mn = e[s] > p ? p : e[s];
        e[s] = keepmax ? mx : mn;
      }
    }
    // j=2,1 fused in-register
    cswap(e[0], e[2], d); cswap(e[1], e[3], d);
    cswap(e[0], e[1], d); cswap(e[2], e[3], d);
  }
  // output directly from registers; whole quad lies on one side of KK (KK%4==0)
#pragma unroll
  for (int s = 0; s < 4; ++s) {
    const int p = b + s;
    u64 kv = e[s];
    int i = (int)(~(unsigned)kv);
    unsigned hi = (unsigned)(kv >> 32);
    unsigned ub = (hi & 0x80000000u) ? (hi ^ 0x80000000u) : ~hi;
    float sc = __uint_as_float(ub);
    int ed = g * EPG_ + i;
    int r = ei[ed], c = ei[EE_ + ed];
    if (p < KK_) {
      out[O_CW + g * KK_ + p] = sc;
      kg[g * KK_ + p] = ed;
      cmask[r] = 1; cmask[c] = 1;
    } else {
      int q = p - KK_;
      out[O_DW + g * KK_ + q] = -sc;
      dg[g * KK_ + q] = ed;
      dmask[r] = 1; dmask[c] = 1;
    }
  }
}

// ---------------- inclusive scan of masks -> nid (cumsum-1); 1 block per mask ----------------
__global__ __launch_bounds__(1024) void scan_kernel(const int* __restrict__ masks, int* __restrict__ nids) {
  const int which = blockIdx.x;
  const int* m = masks + which * NN_;
  int* nid = nids + which * NN_;
  const int tid = threadIdx.x;
  const int base = tid * 32;
  int local[32];
  int sum = 0;
#pragma unroll
  for (int j = 0; j < 32; ++j) { local[j] = m[base + j]; sum += local[j]; }
  __shared__ int ps[1024];
  ps[tid] = sum;
  __syncthreads();
  for (int off = 1; off < 1024; off <<= 1) {
    int v = (tid >= off) ? ps[tid - off] : 0;
    __syncthreads();
    ps[tid] += v;
    __syncthreads();
  }
  int run = ps[tid] - sum;
#pragma unroll
  for (int j = 0; j < 32; ++j) { run += local[j]; nid[base + j] = run - 1; }
}

// ---------------- final gathers ----------------
__global__ __launch_bounds__(256) void finalize_kernel(const int* __restrict__ kg, const int* __restrict__ dg,
                                                       const int* __restrict__ ei,
                                                       const int* __restrict__ nid_c, const int* __restrict__ nid_d,
                                                       const int* __restrict__ cmask, const int* __restrict__ dmask,
                                                       float* __restrict__ out) {
  const int p = blockIdx.x * 256 + threadIdx.x;
  int e = kg[p];
  out[O_CEI + p]       = (float)nid_c[ei[e]];
  out[O_CEI + GK_ + p] = (float)nid_c[ei[EE_ + e]];
  int e2 = dg[p];
  out[O_FEI + p]       = (float)nid_d[ei[e2]];
  out[O_FEI + GK_ + p] = (float)nid_d[ei[EE_ + e2]];
  if (p < NN_) {
    out[O_CM + p] = (float)cmask[p];
    out[O_DM + p] = (float)dmask[p];
  }
}

extern "C" void kernel_launch(void* const* d_in, const int* in_sizes, int n_in,
                              void* d_out, int out_size, void* d_ws, size_t ws_size,
                              hipStream_t stream) {
  (void)in_sizes; (void)n_in; (void)out_size; (void)ws_size;
  const float* x   = (const float*)d_in[0];
  const float* ea  = (const float*)d_in[1];
  const float* W11 = (const float*)d_in[2];
  const float* b11 = (const float*)d_in[3];
  const float* W12 = (const float*)d_in[4];
  const float* W13 = (const float*)d_in[5];
  const float* b13 = (const float*)d_in[6];
  const float* W21 = (const float*)d_in[7];
  const float* b21 = (const float*)d_in[8];
  const float* W22 = (const float*)d_in[9];
  const float* W23 = (const float*)d_in[10];
  const float* b23 = (const float*)d_in[11];
  const float* Wm1 = (const float*)d_in[12];
  const float* bm1 = (const float*)d_in[13];
  const float* Wm2 = (const float*)d_in[14];
  const float* bm2 = (const float*)d_in[15];
  const int*   ei  = (const int*)d_in[16];
  float* out = (float*)d_out;
  float* ws  = (float*)d_ws;

  // workspace (float offsets), phase-overlapped:
  //   MT  [0, 8388608)          32 MB   (dead after mm_agg #2)
  //   Wc  [8388608, 8421376)    128 KB  adjacent to MT -> single fused memset
  //   buf [8421376, 14712832)   24 MB   (dead after mm_agg #2)
  //   pq  [0, 16777216)         64 MB   overlaps MT/Wc/buf, written after all dead
  //   h_c [16777216, 18874368)  8 MB
  //   ints from 18874368: kg GK, dg GK, cmask N, dmask N, nid_c N, nid_d N
  float* MT  = ws;
  float* Wc  = ws + 8388608;
  float* buf = ws + 8421376;
  float* pq  = ws;
  float* h_c = ws + 16777216;
  int* kg    = (int*)(ws + 18874368);
  int* dg    = kg + GK_;
  int* cmask = dg + GK_;
  int* dmask = cmask + NN_;
  int* nid_c = dmask + NN_;
  int* nid_d = nid_c + NN_;

  (void)hipMemsetAsync(MT, 0, (size_t)(8388608 + 32768) * sizeof(float), stream);  // MT + Wc
  (void)hipMemsetAsync(cmask, 0, 2 * NN_ * sizeof(int), stream);

  build_M<<<EE_ / 256, 256, 0, stream>>>(ei, ea, MT, Wc);

  GemmCfg c1{};
  c1.w[0] = W11; c1.w[1] = W12; c1.w[2] = W13;
  c1.b[0] = b11; c1.b[1] = nullptr; c1.b[2] = b13;
  c1.wstride = 64;
  gemm_k64<<<512, 256, 0, stream>>>(x, 64, c1, 3, buf, 192);

  mm_agg<<<512, 256, 0, stream>>>(MT, buf, Wc, h_c, /*relu=*/1);

  GemmCfg c2{};
  c2.w[0] = W21; c2.w[1] = W22; c2.w[2] = W23;
  c2.b[0] = b21; c2.b[1] = nullptr; c2.b[2] = b23;
  c2.wstride = 64;
  gemm_k64<<<512, 256, 0, stream>>>(h_c, 64, c2, 3, buf, 192);

  mm_agg<<<512, 256, 0, stream>>>(MT, buf, Wc, h_c, /*relu=*/0);

  GemmCfg c3{};
  for (int cb = 0; cb < 4; ++cb) { c3.w[cb] = Wm1 + cb * 64 * 128;            c3.b[cb] = bm1 + cb * 64; }
  for (int cb = 4; cb < 8; ++cb) { c3.w[cb] = Wm1 + (cb - 4) * 64 * 128 + 64; c3.b[cb] = nullptr; }
  c3.wstride = 128;
  gemm_k64<<<512, 256, 0, stream>>>(h_c, 64, c3, 8, pq, 512);

  score_v4<<<512, 256, 0, stream>>>(pq, ei, Wm2, bm2, out);

  sort_kernel<<<G_, 1024, 0, stream>>>(out, ei, kg, dg, cmask, dmask);

  scan_kernel<<<2, 1024, 0, stream>>>(cmask, nid_c);

  finalize_kernel<<<GK_ / 256, 256, 0, stream>>>(kg, dg, ei, nid_c, nid_d, cmask, dmask, out);
}